// Round 6
// baseline (90.248 us; speedup 1.0000x reference)
//
#include <hip/hip_runtime.h>

#define K_ITERS 20
#define MU_CONST 0.05f
#define BN 128
#define NB 8            // batches per block (512 blocks * 8 = 4096)
#define NBLOCKS 512
#define YSTRIDE 24      // float stride between 16-float y slices (bank spread)

typedef float v4f __attribute__((ext_vector_type(4)));
typedef __attribute__((address_space(1))) const v4f gc4;   // global const float4
typedef __attribute__((address_space(1))) v4f g4;          // global float4
typedef const __attribute__((address_space(1))) void* gas_ptr;
typedef __attribute__((address_space(3))) void* las_ptr;

// DPP butterfly add step (pure VALU cross-lane; ctrl must be immediate).
template <int CTRL>
__device__ __forceinline__ float dpp_add(float v) {
    int x = __builtin_amdgcn_update_dpp(0, __float_as_int(v), CTRL, 0xF, 0xF, true);
    return v + __int_as_float(x);
}
// sum over the 8 lanes sharing a row-quad (lane bits [2:0] = col-group g)
__device__ __forceinline__ float reduce8(float v) {
    v = dpp_add<0xB1>(v);   // quad_perm xor1
    v = dpp_add<0x4E>(v);   // quad_perm xor2
    v = dpp_add<0x141>(v);  // row_half_mirror
    return v;
}

// 512 persistent blocks x 256 threads (2 blocks/CU, 8 waves/CU).
// Lane (wv,q,g): rows wv*32+q*4+{0..3}, cols g*16+{0..15} -> 16 float4 of w
// in registers. Next batch's w drip-feeds into lds_w via global_load_lds
// (1 KiB contiguous per inst, one inst per wave per iteration) and is copied
// to registers at the batch switch (swizzled ds_read_b128).
__global__ __launch_bounds__(256, 2) void nag_kernel(
    const float* __restrict__ w,
    const float* __restrict__ bvec,
    const float* __restrict__ s_ptr,
    float* __restrict__ out,
    int B)
{
    __shared__ __align__(16) float lds_w[BN * BN];        // 64 KiB stage
    __shared__ __align__(16) float y_lds[2][8 * YSTRIDE]; // ping-pong y

    const int t    = threadIdx.x;     // 0..255
    const int lane = t & 63;
    const int wv   = t >> 6;          // wave 0..3
    const int q    = (t >> 3) & 7;    // row-quad within wave
    const int g    = t & 7;           // col-group (16 cols)
    const int row0   = wv * 32 + q * 4;
    const int wslice = (row0 >> 4) * YSTRIDE + (q & 3) * 4;  // y write offset
    const int rbase  = g * YSTRIDE;                          // y read offset

    const float s     = *s_ptr;
    const float sqms  = sqrtf(MU_CONST * s);
    const float alpha = (1.0f - sqms) / (1.0f + sqms);
    const float ap1   = 1.0f + alpha;

    const int base = blockIdx.x * NB;

    v4f w4[4][4];           // current batch's w rows (single-buffered in regs)
    v4f ba, bbuf;           // b double-buffer
    const v4f* lw4 = (const v4f*)lds_w;

    // One 1 KiB stage chunk: inst covers rows 2*inst, 2*inst+1 contiguously.
    // LDS dst linear (wave-uniform base + lane*16); XOR swizzle applied on the
    // per-lane GLOBAL source so the read-back below un-swizzles (both-sides).
    auto stage_chunk = [&](const float* wb, int cc) {
        const int inst = wv * 16 + cc;            // 0..63
        const int rho  = inst * 2 + (lane >> 5);  // row this lane feeds
        const int c4   = lane & 31;               // float4 col (linear LDS)
        const int G    = rho * 32 + (c4 ^ (rho & 7));
        __builtin_amdgcn_global_load_lds((gas_ptr)(wb + (size_t)G * 4),
                                         (las_ptr)(lds_w + inst * 256), 16, 0, 0);
    };

    // LDS (staged, swizzled) -> registers: rows row0..row0+3, f4-cols g*4+k.
    auto copy_regs = [&]() {
#pragma unroll
        for (int rr = 0; rr < 4; ++rr) {
            const int rho = row0 + rr;
            const int sw  = rho & 7;
#pragma unroll
            for (int k = 0; k < 4; ++k)
                w4[rr][k] = lw4[rho * 32 + ((g * 4 + k) ^ sw)];
        }
    };

    auto load_b = [&](v4f& br, int nb_) {
        br = *(const gc4*)(bvec + (size_t)nb_ * BN + row0);
    };

    auto body = [&](v4f& brc, v4f& brn, int batch, bool pf) {
        const float br0 = brc.x, br1 = brc.y, br2 = brc.z, br3 = brc.w;
        const float* wbn = w + (size_t)(batch + 1) * (BN * BN);

        // closed-form step 1 (y0 = 0): x1 = s*b, y1 = (1+alpha)*x1
        float xs[4], ys[4];
        xs[0] = s * br0; xs[1] = s * br1; xs[2] = s * br2; xs[3] = s * br3;
#pragma unroll
        for (int rho = 0; rho < 4; ++rho) ys[rho] = ap1 * xs[rho];
        if (g == 0)
            *reinterpret_cast<v4f*>(&y_lds[0][wslice]) =
                (v4f){ys[0], ys[1], ys[2], ys[3]};

        if (pf) load_b(brn, batch + 1);

        __builtin_amdgcn_sched_barrier(0);
        asm volatile("s_waitcnt lgkmcnt(0)");
        __builtin_amdgcn_s_barrier();
        __builtin_amdgcn_sched_barrier(0);

#pragma unroll 2
        for (int it = 1; it < K_ITERS; ++it) {
            const float* yb = &y_lds[(it + 1) & 1][rbase];
            v4f yv[4];
#pragma unroll
            for (int k = 0; k < 4; ++k)
                yv[k] = *reinterpret_cast<const v4f*>(yb + k * 4);

            // drip-feed: one 1 KiB stage inst per wave per iteration (1..16)
            if (pf && it <= 16) stage_chunk(wbn, it - 1);

            float br_[4] = {br0, br1, br2, br3};
#pragma unroll
            for (int rho = 0; rho < 4; ++rho) {
                float p = w4[rho][0].x * yv[0].x;
                p = fmaf(w4[rho][0].y, yv[0].y, p);
                p = fmaf(w4[rho][0].z, yv[0].z, p);
                p = fmaf(w4[rho][0].w, yv[0].w, p);
                p = fmaf(w4[rho][1].x, yv[1].x, p);
                p = fmaf(w4[rho][1].y, yv[1].y, p);
                p = fmaf(w4[rho][1].z, yv[1].z, p);
                p = fmaf(w4[rho][1].w, yv[1].w, p);
                p = fmaf(w4[rho][2].x, yv[2].x, p);
                p = fmaf(w4[rho][2].y, yv[2].y, p);
                p = fmaf(w4[rho][2].z, yv[2].z, p);
                p = fmaf(w4[rho][2].w, yv[2].w, p);
                p = fmaf(w4[rho][3].x, yv[3].x, p);
                p = fmaf(w4[rho][3].y, yv[3].y, p);
                p = fmaf(w4[rho][3].z, yv[3].z, p);
                p = fmaf(w4[rho][3].w, yv[3].w, p);
                const float d  = reduce8(p);           // full 128-col dot
                const float xn = fmaf(-s, d - br_[rho], ys[rho]);
                ys[rho] = fmaf(ap1, xn, -(alpha * xs[rho]));
                xs[rho] = xn;
            }

            if (it != K_ITERS - 1 && g == 0)
                *reinterpret_cast<v4f*>(&y_lds[it & 1][wslice]) =
                    (v4f){ys[0], ys[1], ys[2], ys[3]};

            // raw barrier: drains LDS only; stage vmcnt stays in flight
            __builtin_amdgcn_sched_barrier(0);
            asm volatile("s_waitcnt lgkmcnt(0)");
            __builtin_amdgcn_s_barrier();
            __builtin_amdgcn_sched_barrier(0);
        }

        // outputs: x then y, each B*BN flat; rows row0..row0+3 contiguous
        const size_t ob = (size_t)batch * BN + row0;
        if (g == 0)
            *(g4*)(out + ob) = (v4f){xs[0], xs[1], xs[2], xs[3]};
        else if (g == 1)
            *(g4*)(out + (size_t)B * BN + ob) = (v4f){ys[0], ys[1], ys[2], ys[3]};

        // batch switch: drain stage ONCE, copy staged w to regs
        if (pf) {
            __builtin_amdgcn_sched_barrier(0);
            asm volatile("s_waitcnt vmcnt(0)");
            __builtin_amdgcn_s_barrier();          // staged tile visible
            __builtin_amdgcn_sched_barrier(0);
            copy_regs();
            __builtin_amdgcn_sched_barrier(0);
            asm volatile("s_waitcnt lgkmcnt(0)");
            __builtin_amdgcn_s_barrier();          // copies done -> lds_w free
            __builtin_amdgcn_sched_barrier(0);
        }
    };

    // ---- prologue: stage batch 0 in one burst, copy to regs ----
    load_b(ba, base);
    {
        const float* wb0 = w + (size_t)base * (BN * BN);
#pragma unroll
        for (int cc = 0; cc < 16; ++cc) stage_chunk(wb0, cc);
    }
    __builtin_amdgcn_sched_barrier(0);
    asm volatile("s_waitcnt vmcnt(0)");
    __builtin_amdgcn_s_barrier();
    __builtin_amdgcn_sched_barrier(0);
    copy_regs();
    __builtin_amdgcn_sched_barrier(0);
    asm volatile("s_waitcnt lgkmcnt(0)");
    __builtin_amdgcn_s_barrier();
    __builtin_amdgcn_sched_barrier(0);

#pragma unroll 1
    for (int i2 = 0; i2 < NB / 2; ++i2) {
        body(ba, bbuf, base + 2 * i2, true);
        body(bbuf, ba, base + 2 * i2 + 1, (2 * i2 + 2) < NB);
    }
}

extern "C" void kernel_launch(void* const* d_in, const int* in_sizes, int n_in,
                              void* d_out, int out_size, void* d_ws, size_t ws_size,
                              hipStream_t stream) {
    const float* w = (const float*)d_in[0];
    const float* b = (const float*)d_in[1];
    const float* s = (const float*)d_in[2];
    float* out = (float*)d_out;
    const int B = in_sizes[1] / BN;    // 4096
    nag_kernel<<<dim3(NBLOCKS), dim3(256), 0, stream>>>(w, b, s, out, B);
}

// Round 7
// 60.672 us; speedup vs baseline: 1.4875x; 1.4875x over previous
//
#include <hip/hip_runtime.h>

#define K_ITERS 20
#define MU_CONST 0.05f
#define BN 128
#define YSTRIDE 24      // float stride between 16-float y slices (bank spread)

typedef float v4f __attribute__((ext_vector_type(4)));
typedef __attribute__((address_space(1))) const v4f gc4;   // global const float4
typedef __attribute__((address_space(1))) v4f g4;          // global float4

// DPP butterfly add step (pure VALU cross-lane; ctrl must be immediate).
template <int CTRL>
__device__ __forceinline__ float dpp_add(float v) {
    int x = __builtin_amdgcn_update_dpp(0, __float_as_int(v), CTRL, 0xF, 0xF, true);
    return v + __int_as_float(x);
}
// sum over the 8 lanes sharing a row-quad (lane bits [2:0] = col-group g)
__device__ __forceinline__ float reduce8(float v) {
    v = dpp_add<0xB1>(v);   // quad_perm xor1
    v = dpp_add<0x4E>(v);   // quad_perm xor2
    v = dpp_add<0x141>(v);  // row_half_mirror
    return v;
}

// One block per batch (4096 blocks). 256 threads, <=128 VGPR -> 4 blocks/CU.
// Block-level pipelining provides the load/compute overlap: as blocks retire,
// freshly launched blocks issue their w-loads while resident blocks compute.
// Lane (wv,q,g): rows wv*32+q*4+{0..3}, cols g*16+{0..15} -> 16 float4 of w.
__global__ __launch_bounds__(256, 4) void nag_kernel(
    const float* __restrict__ w,
    const float* __restrict__ bvec,
    const float* __restrict__ s_ptr,
    float* __restrict__ out,
    int B)
{
    __shared__ __align__(16) float y_lds[2][8 * YSTRIDE];   // ping-pong y

    const int t  = threadIdx.x;       // 0..255
    const int wv = t >> 6;            // wave 0..3
    const int q  = (t >> 3) & 7;      // row-quad within wave
    const int g  = t & 7;             // col-group (16 cols)
    const int row0   = wv * 32 + q * 4;
    const int wslice = (row0 >> 4) * YSTRIDE + (q & 3) * 4;  // y write offset
    const int rbase  = g * YSTRIDE;                          // y read offset

    const int batch = blockIdx.x;

    // issue all global loads up front: 16x dwordx4 (w) + 1x dwordx4 (b) + s
    v4f w4[4][4];
    const gc4* wp = (const gc4*)(w + (size_t)batch * (BN * BN)
                                   + (size_t)row0 * BN + g * 16);
#pragma unroll
    for (int rho = 0; rho < 4; ++rho)
#pragma unroll
        for (int k = 0; k < 4; ++k)
            w4[rho][k] = wp[rho * 32 + k];

    const v4f br4 = *(const gc4*)(bvec + (size_t)batch * BN + row0);
    const float br_[4] = {br4.x, br4.y, br4.z, br4.w};

    const float s     = *s_ptr;
    const float sqms  = sqrtf(MU_CONST * s);
    const float alpha = (1.0f - sqms) / (1.0f + sqms);
    const float ap1   = 1.0f + alpha;

    // closed-form step 1 (y0 = 0): x1 = s*b, y1 = (1+alpha)*x1
    float xs[4], ys[4];
#pragma unroll
    for (int rho = 0; rho < 4; ++rho) {
        xs[rho] = s * br_[rho];
        ys[rho] = ap1 * xs[rho];
    }
    if (g == 0)
        *reinterpret_cast<v4f*>(&y_lds[0][wslice]) =
            (v4f){ys[0], ys[1], ys[2], ys[3]};
    __syncthreads();

#pragma unroll 2
    for (int it = 1; it < K_ITERS; ++it) {
        const float* yb = &y_lds[(it + 1) & 1][rbase];
        v4f yv[4];
#pragma unroll
        for (int k = 0; k < 4; ++k)
            yv[k] = *reinterpret_cast<const v4f*>(yb + k * 4);

#pragma unroll
        for (int rho = 0; rho < 4; ++rho) {
            float p = w4[rho][0].x * yv[0].x;
            p = fmaf(w4[rho][0].y, yv[0].y, p);
            p = fmaf(w4[rho][0].z, yv[0].z, p);
            p = fmaf(w4[rho][0].w, yv[0].w, p);
            p = fmaf(w4[rho][1].x, yv[1].x, p);
            p = fmaf(w4[rho][1].y, yv[1].y, p);
            p = fmaf(w4[rho][1].z, yv[1].z, p);
            p = fmaf(w4[rho][1].w, yv[1].w, p);
            p = fmaf(w4[rho][2].x, yv[2].x, p);
            p = fmaf(w4[rho][2].y, yv[2].y, p);
            p = fmaf(w4[rho][2].z, yv[2].z, p);
            p = fmaf(w4[rho][2].w, yv[2].w, p);
            p = fmaf(w4[rho][3].x, yv[3].x, p);
            p = fmaf(w4[rho][3].y, yv[3].y, p);
            p = fmaf(w4[rho][3].z, yv[3].z, p);
            p = fmaf(w4[rho][3].w, yv[3].w, p);
            const float d  = reduce8(p);           // full 128-col dot
            const float xn = fmaf(-s, d - br_[rho], ys[rho]);
            ys[rho] = fmaf(ap1, xn, -(alpha * xs[rho]));
            xs[rho] = xn;
        }

        if (it != K_ITERS - 1 && g == 0)
            *reinterpret_cast<v4f*>(&y_lds[it & 1][wslice]) =
                (v4f){ys[0], ys[1], ys[2], ys[3]};
        __syncthreads();
    }

    // outputs: x then y, each B*BN flat; rows row0..row0+3 contiguous
    const size_t ob = (size_t)batch * BN + row0;
    if (g == 0)
        *(g4*)(out + ob) = (v4f){xs[0], xs[1], xs[2], xs[3]};
    else if (g == 1)
        *(g4*)(out + (size_t)B * BN + ob) = (v4f){ys[0], ys[1], ys[2], ys[3]};
}

extern "C" void kernel_launch(void* const* d_in, const int* in_sizes, int n_in,
                              void* d_out, int out_size, void* d_ws, size_t ws_size,
                              hipStream_t stream) {
    const float* w = (const float*)d_in[0];
    const float* b = (const float*)d_in[1];
    const float* s = (const float*)d_in[2];
    float* out = (float*)d_out;
    const int B = in_sizes[1] / BN;    // 4096
    nag_kernel<<<dim3(B), dim3(256), 0, stream>>>(w, b, s, out, B);
}